// Round 21
// baseline (239.546 us; speedup 1.0000x reference)
//
#include <hip/hip_runtime.h>
#include <hip/hip_bf16.h>

// Problem constants (fixed by reference setup_inputs)
#define S_ROWS 4096
#define Q_ROWS 8192
#define DIM 256
#define N_SEL 19       // selection events (20 scan steps)
#define COLSPLIT 32    // phase-B column splits (128 cols per block)
#define BM 128         // phase-B rows per block
#define LDSU 40        // phase-B LDS row stride (ushorts)
#define CB 32          // phase-C blocks
#define CT 1024        // phase-C threads per block
#define CR 256         // phase-C rows per block (4 threads per row)
#define SLOTS 4        // candidate slots per block per iteration
#define PKS 16         // packed-word stride in uint64 = 128B/line (R18 lesson)

typedef __attribute__((ext_vector_type(8))) short bf16x8;
typedef __attribute__((ext_vector_type(4))) float f32x4;

// Workspace layout (floats)
#define WS_INV_Q 0
#define WS_QQ    (WS_INV_Q + Q_ROWS)
#define WS_INV_S (WS_QQ + Q_ROWS)
#define WS_PP    (WS_INV_S + S_ROWS)
#define WS_TOP3P (WS_PP + S_ROWS)                    // [COLSPLIT][Q_ROWS][4]
#define WS_CANDU (WS_TOP3P + COLSPLIT * Q_ROWS * 4)  // [32][CB*SLOTS]
#define WS_CANDI (WS_CANDU + 32 * CB * SLOTS)        // [32][CB*SLOTS] (int)
#define WS_PACKED (WS_CANDI + 32 * CB * SLOTS)       // uint64 [32*CB*PKS]

// ---------------------------------------------------------------------------
// Row L2-norms for BOTH inputs + per-launch init (packed sentinels, ones
// output) in ONE launch. Grid covers (Q+S) waves = 12288 >= all init ranges.
__global__ void norm_rows_all(const float* __restrict__ qf, const float* __restrict__ sf,
                              float* __restrict__ inv_q, float* __restrict__ qq,
                              float* __restrict__ inv_s, float* __restrict__ pp,
                              unsigned long long* __restrict__ packed,
                              float* __restrict__ out, int n_extra) {
    int gt = blockIdx.x * blockDim.x + threadIdx.x;
    if (gt < 32 * CB) packed[gt * PKS] = ~0ull;       // R12 lesson: grid must cover
    if (gt < n_extra) out[Q_ROWS + gt] = 1.0f;        // every init range
    int w = gt >> 6;
    int lane = threadIdx.x & 63;
    if (w >= Q_ROWS + S_ROWS) return;
    const float* x;
    float *inv, *ssq;
    if (w < Q_ROWS) { x = qf + (size_t)w * DIM; inv = inv_q + w; ssq = qq + w; }
    else { int v2 = w - Q_ROWS; x = sf + (size_t)v2 * DIM; inv = inv_s + v2; ssq = pp + v2; }
    float4 v = reinterpret_cast<const float4*>(x)[lane];
    float s = v.x * v.x + v.y * v.y + v.z * v.z + v.w * v.w;
#pragma unroll
    for (int o = 1; o < 64; o <<= 1) s += __shfl_xor(s, o, 64);
    float invn = 1.0f / sqrtf(s);
    float t = v.x * invn; float u = t * t;
    t = v.y * invn; u += t * t;
    t = v.z * invn; u += t * t;
    t = v.w * invn; u += t * t;
#pragma unroll
    for (int o = 1; o < 64; o <<= 1) u += __shfl_xor(u, o, 64);
    if (lane == 0) { *inv = invn; *ssq = u; }
}

// ---------------------------------------------------------------------------
__device__ __forceinline__ void t3ins(float (&t3)[3], float d) {
    float mx = fmaxf(fmaxf(t3[0], t3[1]), t3[2]);
    if (d < mx) {
        if (t3[0] == mx) t3[0] = d;
        else if (t3[1] == mx) t3[1] = d;
        else t3[2] = d;
    }
}

__device__ __forceinline__ float smean3(float a, float b, float c) {
    float lo = fminf(fminf(a, b), c);
    float hi = fmaxf(fmaxf(a, b), c);
    float md = fminf(fmaxf(a, b), fminf(fmaxf(b, c), fmaxf(a, c)));
    return ((lo + md) + hi) * (1.0f / 3.0f);
}

// RNE pair conversions -> v_cvt_pk_bf16_f32 (R19).
__device__ __forceinline__ unsigned pk_hi(float x, float y, float& rx, float& ry) {
    __hip_bfloat162 h = __float22bfloat162_rn(make_float2(x, y));
    float2 f = __bfloat1622float2(h);
    rx = x - f.x; ry = y - f.y;
    return *reinterpret_cast<unsigned*>(&h);
}
__device__ __forceinline__ unsigned pk_rn(float x, float y) {
    __hip_bfloat162 h = __float22bfloat162_rn(make_float2(x, y));
    return *reinterpret_cast<unsigned*>(&h);
}

// ---------------------------------------------------------------------------
// Phase B: split-precision bf16 MFMA (R17-R20 arithmetic, bitwise-identical),
// NOW double-buffered LDS with ONE barrier per kt (was 2): STAGE(kt+1)->buf^1
// overlaps compute(kt)<-buf across waves. The buffer STAGE(kt+1) overwrites
// was last read in compute(kt-1), finished by all threads pre-barrier ->
// single barrier is sufficient. No cross-barrier register state -> no spill
// path (R10 lesson). LDS 40->80KB (2 blocks/CU).
__launch_bounds__(256, 2)
__global__ void knn_support_kernel(const float* __restrict__ qf, const float* __restrict__ sf,
                                   const float* __restrict__ inv_q, const float* __restrict__ inv_s,
                                   const float* __restrict__ qq, const float* __restrict__ pp,
                                   float* __restrict__ top3part) {
    __shared__ __align__(16) unsigned short Ah[2][BM * LDSU];
    __shared__ __align__(16) unsigned short Al[2][BM * LDSU];
    __shared__ __align__(16) unsigned short Bh[2][BM * LDSU];
    __shared__ __align__(16) unsigned short Bl[2][BM * LDSU];

    int b0 = blockIdx.x;
    int rb = (b0 & 63) * BM;
    int cs = b0 >> 6;            // 0..31
    int cb = cs * 128;
    int tid = threadIdx.x;
    int lane = tid & 63, wv = tid >> 6;
    int g = lane >> 4, c0l = lane & 15;

    f32x4 acc[2][8];
#pragma unroll
    for (int rt = 0; rt < 2; ++rt)
#pragma unroll
        for (int ct = 0; ct < 8; ++ct) acc[rt][ct] = (f32x4){0.f, 0.f, 0.f, 0.f};

    auto STAGE = [&](int kt) {
        int ko = kt * 32;
        int bf = kt & 1;
#pragma unroll
        for (int q = 0; q < 4; ++q) {
            int idx = q * 256 + tid;
            int row = idx >> 3, f4 = idx & 7;
            float4 a = *reinterpret_cast<const float4*>(qf + (size_t)(rb + row) * DIM + ko + f4 * 4);
            float4 b = *reinterpret_cast<const float4*>(sf + (size_t)(cb + row) * DIM + ko + f4 * 4);
            float r0, r1, r2, r3;
            unsigned ah0 = pk_hi(a.x, a.y, r0, r1), ah1 = pk_hi(a.z, a.w, r2, r3);
            unsigned al0 = pk_rn(r0, r1), al1 = pk_rn(r2, r3);
            unsigned bh0 = pk_hi(b.x, b.y, r0, r1), bh1 = pk_hi(b.z, b.w, r2, r3);
            unsigned bl0 = pk_rn(r0, r1), bl1 = pk_rn(r2, r3);
            *reinterpret_cast<uint2*>(&Ah[bf][row * LDSU + f4 * 4]) = make_uint2(ah0, ah1);
            *reinterpret_cast<uint2*>(&Al[bf][row * LDSU + f4 * 4]) = make_uint2(al0, al1);
            *reinterpret_cast<uint2*>(&Bh[bf][row * LDSU + f4 * 4]) = make_uint2(bh0, bh1);
            *reinterpret_cast<uint2*>(&Bl[bf][row * LDSU + f4 * 4]) = make_uint2(bl0, bl1);
        }
    };

    STAGE(0);
    for (int kt = 0; kt < 8; ++kt) {
        __syncthreads();             // staged(kt) visible; buf^1's old readers done
        if (kt + 1 < 8) STAGE(kt + 1);
        int bf = kt & 1;
        bf16x8 ahi[2], alo[2];
#pragma unroll
        for (int rt = 0; rt < 2; ++rt) {
            int arow = wv * 32 + rt * 16 + c0l;
            ahi[rt] = *reinterpret_cast<const bf16x8*>(&Ah[bf][arow * LDSU + g * 8]);
            alo[rt] = *reinterpret_cast<const bf16x8*>(&Al[bf][arow * LDSU + g * 8]);
        }
#pragma unroll
        for (int ct = 0; ct < 8; ++ct) {
            int brow = ct * 16 + c0l;
            bf16x8 bhi = *reinterpret_cast<const bf16x8*>(&Bh[bf][brow * LDSU + g * 8]);
            bf16x8 blo = *reinterpret_cast<const bf16x8*>(&Bl[bf][brow * LDSU + g * 8]);
#pragma unroll
            for (int rt = 0; rt < 2; ++rt) {
                acc[rt][ct] = __builtin_amdgcn_mfma_f32_16x16x32_bf16(ahi[rt], bhi, acc[rt][ct], 0, 0, 0);
                acc[rt][ct] = __builtin_amdgcn_mfma_f32_16x16x32_bf16(ahi[rt], blo, acc[rt][ct], 0, 0, 0);
                acc[rt][ct] = __builtin_amdgcn_mfma_f32_16x16x32_bf16(alo[rt], bhi, acc[rt][ct], 0, 0, 0);
            }
        }
    }

    float ivb[8], ppc[8];
#pragma unroll
    for (int ct = 0; ct < 8; ++ct) {
        ivb[ct] = inv_s[cb + ct * 16 + c0l];
        ppc[ct] = pp[cb + ct * 16 + c0l];
    }
    float t3r[2][4][3];
#pragma unroll
    for (int rt = 0; rt < 2; ++rt)
#pragma unroll
        for (int v = 0; v < 4; ++v)
            t3r[rt][v][0] = t3r[rt][v][1] = t3r[rt][v][2] = INFINITY;
#pragma unroll
    for (int rt = 0; rt < 2; ++rt) {
        float iva[4], qqr[4];
#pragma unroll
        for (int v = 0; v < 4; ++v) {
            int row = rb + wv * 32 + rt * 16 + g * 4 + v;
            iva[v] = inv_q[row];
            qqr[v] = qq[row];
        }
#pragma unroll
        for (int ct = 0; ct < 8; ++ct) {
#pragma unroll
            for (int v = 0; v < 4; ++v) {
                float dot = acc[rt][ct][v] * iva[v] * ivb[ct];
                float d2 = qqr[v] + ppc[ct] - 2.0f * dot;
                float d = sqrtf(fmaxf(d2, 1e-12f));
                t3ins(t3r[rt][v], d);
            }
        }
    }
#pragma unroll
    for (int off = 1; off < 16; off <<= 1) {
#pragma unroll
        for (int rt = 0; rt < 2; ++rt)
#pragma unroll
            for (int v = 0; v < 4; ++v) {
                float o0 = __shfl_xor(t3r[rt][v][0], off, 64);
                float o1 = __shfl_xor(t3r[rt][v][1], off, 64);
                float o2 = __shfl_xor(t3r[rt][v][2], off, 64);
                t3ins(t3r[rt][v], o0);
                t3ins(t3r[rt][v], o1);
                t3ins(t3r[rt][v], o2);
            }
    }
    if (c0l == 0) {
#pragma unroll
        for (int rt = 0; rt < 2; ++rt)
#pragma unroll
            for (int v = 0; v < 4; ++v) {
                int row = rb + wv * 32 + rt * 16 + g * 4 + v;
                float* dst = top3part + ((size_t)cs * Q_ROWS + row) * 4;
                dst[0] = t3r[rt][v][0]; dst[1] = t3r[rt][v][1];
                dst[2] = t3r[rt][v][2]; dst[3] = 0.0f;
            }
    }
}

// ---------------------------------------------------------------------------
// Phase C (R20 proven, ~105us): FROZEN. Packed-word flag barrier + register-
// resident pre-scaled rows.
__launch_bounds__(1024)
__global__ void iterate_select(const float* __restrict__ qf, const float* __restrict__ inv_q,
                               const float* __restrict__ qq, const float* __restrict__ top3part,
                               float* __restrict__ out, float* __restrict__ candU,
                               int* __restrict__ candI, unsigned long long* __restrict__ packed) {
    __shared__ float t3s[CR][3];
    __shared__ float qqs[CR], scs[CR];
    __shared__ int kn[CR];
    __shared__ __align__(16) float qfc[DIM];
    __shared__ float red[CT / 64];
    __shared__ float bmin_sh;
    __shared__ unsigned long long pk_sh[CB];
    __shared__ int lidx[16];
    __shared__ int lidx_loc[SLOTS];
    __shared__ int lcnt, ccnt;

    int tid = threadIdx.x;
    int bid = blockIdx.x;
    int rbase = bid * CR;
    int lane = tid & 63, wv = tid >> 6;
    int row = tid >> 2, sub = tid & 3;   // 4 threads per row

    float4 rr[16];
    {
        float si = inv_q[rbase + row];
        const float4* rp = reinterpret_cast<const float4*>(qf + (size_t)(rbase + row) * DIM);
#pragma unroll
        for (int i = 0; i < 16; ++i) {
            float4 v = rp[sub + 4 * i];
            rr[i] = make_float4(v.x * si, v.y * si, v.z * si, v.w * si);
        }
    }
    if (tid < CR) {
        int r = rbase + tid;
        float b3[3] = {INFINITY, INFINITY, INFINITY};
        for (int csq = 0; csq < COLSPLIT; ++csq) {
            const float* p = top3part + ((size_t)csq * Q_ROWS + r) * 4;
            t3ins(b3, p[0]); t3ins(b3, p[1]); t3ins(b3, p[2]);
        }
        t3s[tid][0] = b3[0]; t3s[tid][1] = b3[1]; t3s[tid][2] = b3[2];
        qqs[tid] = qq[r];
        kn[tid] = 0;
    }
    __syncthreads();

    for (int t = 0; t <= N_SEL; ++t) {
        if (t > 0) {
            if (tid == 0) lcnt = 0;
            __syncthreads();
            if (wv == 0) {
                unsigned long long pv = (lane < CB) ? pk_sh[lane] : ~0ull;
                unsigned bb = (lane < CB) ? (unsigned)(pv >> 32) : 0xFFFFFFFFu;
                unsigned mb = bb;
#pragma unroll
                for (int o = 1; o < 64; o <<= 1) mb = min(mb, (unsigned)__shfl_xor((int)mb, o, 64));
                if (lane < CB && bb == mb) {
                    if (!(pv & 1ull)) {
                        int p = atomicAdd(&lcnt, 1);
                        if (p < 16) lidx[p] = (int)((pv >> 1) & 0x7FFFull);
                    } else {
                        for (int s2 = 0; s2 < SLOTS; ++s2) {
                            float u = candU[(t - 1) * CB * SLOTS + lane * SLOTS + s2];
                            if (__float_as_uint(u) == mb) {
                                int p = atomicAdd(&lcnt, 1);
                                if (p < 16) lidx[p] = candI[(t - 1) * CB * SLOTS + lane * SLOTS + s2];
                            }
                        }
                    }
                }
            }
            __syncthreads();
            int m = lcnt < 16 ? lcnt : 16;
            for (int j = 0; j < m; ++j) {
                int c = lidx[j];
                if (tid == 0 && c >= rbase && c < rbase + CR) kn[c - rbase] = 1;
                if (tid < 64) {
                    float4 v = reinterpret_cast<const float4*>(qf + (size_t)c * DIM)[tid];
                    float s = inv_q[c];
                    reinterpret_cast<float4*>(qfc)[tid] = make_float4(v.x * s, v.y * s, v.z * s, v.w * s);
                }
                __syncthreads();
                float qqc = qq[c];
                const float4* cp = reinterpret_cast<const float4*>(qfc);
                float d = 0.0f;
#pragma unroll
                for (int i2 = 0; i2 < 16; ++i2) {
                    float4 w = cp[sub + 4 * i2];
                    d += rr[i2].x * w.x;
                    d += rr[i2].y * w.y;
                    d += rr[i2].z * w.z;
                    d += rr[i2].w * w.w;
                }
                d += __shfl_xor(d, 1, 64);
                d += __shfl_xor(d, 2, 64);
                if (sub == 0) {
                    float d2 = qqs[row] + qqc - 2.0f * d;
                    float dist = sqrtf(fmaxf(d2, 1e-12f));
                    float b3[3] = {t3s[row][0], t3s[row][1], t3s[row][2]};
                    t3ins(b3, dist);
                    t3s[row][0] = b3[0]; t3s[row][1] = b3[1]; t3s[row][2] = b3[2];
                }
                __syncthreads();
            }
            __syncthreads();
        }

        if (t == N_SEL) {
            if (tid < CR)
                out[rbase + tid] = 1.0f - smean3(t3s[tid][0], t3s[tid][1], t3s[tid][2]);
            return;
        }

        if (tid == 0) ccnt = 0;
        if (tid < CR)
            scs[tid] = kn[tid] ? INFINITY : smean3(t3s[tid][0], t3s[tid][1], t3s[tid][2]);
        __syncthreads();

        float mn = (tid < CR) ? scs[tid] : INFINITY;
#pragma unroll
        for (int o = 1; o < 64; o <<= 1) mn = fminf(mn, __shfl_xor(mn, o, 64));
        if (lane == 0) red[wv] = mn;
        __syncthreads();
        if (tid == 0) {
            float v = red[0];
#pragma unroll
            for (int i = 1; i < CT / 64; ++i) v = fminf(v, red[i]);
            bmin_sh = v;
        }
        __syncthreads();
        float bmin = bmin_sh;
        if (tid < CR && scs[tid] == bmin) {
            int p = atomicAdd(&ccnt, 1);
            if (p < SLOTS) {
                candU[t * CB * SLOTS + bid * SLOTS + p] = scs[tid];
                candI[t * CB * SLOTS + bid * SLOTS + p] = rbase + tid;
                lidx_loc[p] = rbase + tid;
            }
        }
        __syncthreads();
        if (tid == 0) {
            for (int p = ccnt; p < SLOTS; ++p) {
                candU[t * CB * SLOTS + bid * SLOTS + p] = INFINITY;
                candI[t * CB * SLOTS + bid * SLOTS + p] = 0;
            }
            unsigned long long pk = ((unsigned long long)__float_as_uint(bmin) << 32)
                                  | ((unsigned long long)(unsigned)lidx_loc[0] << 1)
                                  | (ccnt > 1 ? 1ull : 0ull);
            __hip_atomic_store(&packed[(t * CB + bid) * PKS], pk,
                               __ATOMIC_RELEASE, __HIP_MEMORY_SCOPE_AGENT);
        }
        if (wv == 0) {
            for (;;) {
                unsigned long long pv = (lane < CB)
                    ? __hip_atomic_load(&packed[(t * CB + lane) * PKS], __ATOMIC_RELAXED, __HIP_MEMORY_SCOPE_AGENT)
                    : 0ull;
                bool ok = (lane >= CB) || (pv != ~0ull);
                if (__all(ok)) { if (lane < CB) pk_sh[lane] = pv; break; }
                __builtin_amdgcn_s_sleep(1);
            }
            __builtin_amdgcn_fence(__ATOMIC_ACQUIRE, "agent");
        }
        __syncthreads();
    }
}

// ---------------------------------------------------------------------------
extern "C" void kernel_launch(void* const* d_in, const int* in_sizes, int n_in,
                              void* d_out, int out_size, void* d_ws, size_t ws_size,
                              hipStream_t stream) {
    const float* sfeat = (const float*)d_in[0];
    const float* qfeat = (const float*)d_in[2];
    float* out = (float*)d_out;

    float* ws = (float*)d_ws;
    float* inv_q = ws + WS_INV_Q;
    float* qq    = ws + WS_QQ;
    float* inv_s = ws + WS_INV_S;
    float* pp    = ws + WS_PP;
    float* top3p = ws + WS_TOP3P;
    float* candU = ws + WS_CANDU;
    int* candI   = (int*)(ws + WS_CANDI);
    unsigned long long* packed = (unsigned long long*)(ws + WS_PACKED);

    int n_extra = out_size - Q_ROWS;
    if (n_extra < 0) n_extra = 0;

    norm_rows_all<<<(Q_ROWS + S_ROWS) * 64 / 256, 256, 0, stream>>>(
        qfeat, sfeat, inv_q, qq, inv_s, pp, packed, out, n_extra);
    knn_support_kernel<<<64 * COLSPLIT, 256, 0, stream>>>(qfeat, sfeat, inv_q, inv_s, qq, pp, top3p);

    const float* a0 = qfeat; const float* a1 = inv_q; const float* a2 = qq;
    const float* a3 = top3p; float* a4 = out;
    float* a5 = candU; int* a6 = candI; unsigned long long* a7 = packed;
    void* cargs[] = {&a0, &a1, &a2, &a3, &a4, &a5, &a6, &a7};
    hipLaunchCooperativeKernel(iterate_select, dim3(CB), dim3(CT), cargs, 0, stream);
}

// Round 22
// 220.922 us; speedup vs baseline: 1.0843x; 1.0843x over previous
//
#include <hip/hip_runtime.h>
#include <hip/hip_bf16.h>

// Problem constants (fixed by reference setup_inputs)
#define S_ROWS 4096
#define Q_ROWS 8192
#define DIM 256
#define N_SEL 19       // selection events (20 scan steps)
#define COLSPLIT 32    // phase-B column splits (128 cols per block)
#define BM 128         // phase-B rows per block
#define LDSU 40        // phase-B LDS row stride (ushorts)
#define CB 32          // phase-C blocks
#define CT 1024        // phase-C threads per block
#define CR 256         // phase-C rows per block (4 threads per row)
#define SLOTS 4        // candidate slots per block per iteration
#define PKS 16         // packed-word stride in uint64 = 128B/line (R18 lesson)

typedef __attribute__((ext_vector_type(8))) short bf16x8;
typedef __attribute__((ext_vector_type(4))) float f32x4;

// Workspace layout (floats)
#define WS_INV_Q 0
#define WS_QQ    (WS_INV_Q + Q_ROWS)
#define WS_INV_S (WS_QQ + Q_ROWS)
#define WS_PP    (WS_INV_S + S_ROWS)
#define WS_TOP3P (WS_PP + S_ROWS)                    // [COLSPLIT][Q_ROWS][4]
#define WS_CANDU (WS_TOP3P + COLSPLIT * Q_ROWS * 4)  // [32][CB*SLOTS]
#define WS_CANDI (WS_CANDU + 32 * CB * SLOTS)        // [32][CB*SLOTS] (int)
#define WS_PACKED (WS_CANDI + 32 * CB * SLOTS)       // uint64 [32*CB*PKS]

// ---------------------------------------------------------------------------
// Row L2-norms for BOTH inputs + per-launch init in ONE launch (R21 fusion).
__global__ void norm_rows_all(const float* __restrict__ qf, const float* __restrict__ sf,
                              float* __restrict__ inv_q, float* __restrict__ qq,
                              float* __restrict__ inv_s, float* __restrict__ pp,
                              unsigned long long* __restrict__ packed,
                              float* __restrict__ out, int n_extra) {
    int gt = blockIdx.x * blockDim.x + threadIdx.x;
    if (gt < 32 * CB) packed[gt * PKS] = ~0ull;       // R12 lesson: grid must cover
    if (gt < n_extra) out[Q_ROWS + gt] = 1.0f;        // every init range
    int w = gt >> 6;
    int lane = threadIdx.x & 63;
    if (w >= Q_ROWS + S_ROWS) return;
    const float* x;
    float *inv, *ssq;
    if (w < Q_ROWS) { x = qf + (size_t)w * DIM; inv = inv_q + w; ssq = qq + w; }
    else { int v2 = w - Q_ROWS; x = sf + (size_t)v2 * DIM; inv = inv_s + v2; ssq = pp + v2; }
    float4 v = reinterpret_cast<const float4*>(x)[lane];
    float s = v.x * v.x + v.y * v.y + v.z * v.z + v.w * v.w;
#pragma unroll
    for (int o = 1; o < 64; o <<= 1) s += __shfl_xor(s, o, 64);
    float invn = 1.0f / sqrtf(s);
    float t = v.x * invn; float u = t * t;
    t = v.y * invn; u += t * t;
    t = v.z * invn; u += t * t;
    t = v.w * invn; u += t * t;
#pragma unroll
    for (int o = 1; o < 64; o <<= 1) u += __shfl_xor(u, o, 64);
    if (lane == 0) { *inv = invn; *ssq = u; }
}

// ---------------------------------------------------------------------------
__device__ __forceinline__ void t3ins(float (&t3)[3], float d) {
    float mx = fmaxf(fmaxf(t3[0], t3[1]), t3[2]);
    if (d < mx) {
        if (t3[0] == mx) t3[0] = d;
        else if (t3[1] == mx) t3[1] = d;
        else t3[2] = d;
    }
}

__device__ __forceinline__ float smean3(float a, float b, float c) {
    float lo = fminf(fminf(a, b), c);
    float hi = fmaxf(fmaxf(a, b), c);
    float md = fminf(fmaxf(a, b), fminf(fmaxf(b, c), fmaxf(a, c)));
    return ((lo + md) + hi) * (1.0f / 3.0f);
}

// RNE pair conversions -> v_cvt_pk_bf16_f32 (R19).
__device__ __forceinline__ unsigned pk_hi(float x, float y, float& rx, float& ry) {
    __hip_bfloat162 h = __float22bfloat162_rn(make_float2(x, y));
    float2 f = __bfloat1622float2(h);
    rx = x - f.x; ry = y - f.y;
    return *reinterpret_cast<unsigned*>(&h);
}
__device__ __forceinline__ unsigned pk_rn(float x, float y) {
    __hip_bfloat162 h = __float22bfloat162_rn(make_float2(x, y));
    return *reinterpret_cast<unsigned*>(&h);
}

// ---------------------------------------------------------------------------
// Phase B: R20 EXACT (proven ~85-90us, absmax 0.0): split-precision bf16 MFMA,
// single-buffered 40KB LDS, 2 barriers/kt, 4 blocks/CU. R21 lesson: the
// double-buffered 80KB/1-barrier variant dropped occupancy to 2 blocks/CU
// and REGRESSED to 123us — on this kernel block-level MLP beats barrier count.
__launch_bounds__(256, 2)
__global__ void knn_support_kernel(const float* __restrict__ qf, const float* __restrict__ sf,
                                   const float* __restrict__ inv_q, const float* __restrict__ inv_s,
                                   const float* __restrict__ qq, const float* __restrict__ pp,
                                   float* __restrict__ top3part) {
    __shared__ __align__(16) unsigned short Ah[BM * LDSU];
    __shared__ __align__(16) unsigned short Al[BM * LDSU];
    __shared__ __align__(16) unsigned short Bh[BM * LDSU];
    __shared__ __align__(16) unsigned short Bl[BM * LDSU];

    int b0 = blockIdx.x;
    int rb = (b0 & 63) * BM;
    int cs = b0 >> 6;            // 0..31
    int cb = cs * 128;
    int tid = threadIdx.x;
    int lane = tid & 63, wv = tid >> 6;
    int g = lane >> 4, c0l = lane & 15;

    f32x4 acc[2][8];
#pragma unroll
    for (int rt = 0; rt < 2; ++rt)
#pragma unroll
        for (int ct = 0; ct < 8; ++ct) acc[rt][ct] = (f32x4){0.f, 0.f, 0.f, 0.f};

    for (int kt = 0; kt < 8; ++kt) {
        int ko = kt * 32;
        __syncthreads();
#pragma unroll
        for (int q = 0; q < 4; ++q) {
            int idx = q * 256 + tid;
            int row = idx >> 3, f4 = idx & 7;
            float4 a = *reinterpret_cast<const float4*>(qf + (size_t)(rb + row) * DIM + ko + f4 * 4);
            float4 b = *reinterpret_cast<const float4*>(sf + (size_t)(cb + row) * DIM + ko + f4 * 4);
            float r0, r1, r2, r3;
            unsigned ah0 = pk_hi(a.x, a.y, r0, r1), ah1 = pk_hi(a.z, a.w, r2, r3);
            unsigned al0 = pk_rn(r0, r1), al1 = pk_rn(r2, r3);
            unsigned bh0 = pk_hi(b.x, b.y, r0, r1), bh1 = pk_hi(b.z, b.w, r2, r3);
            unsigned bl0 = pk_rn(r0, r1), bl1 = pk_rn(r2, r3);
            *reinterpret_cast<uint2*>(Ah + row * LDSU + f4 * 4) = make_uint2(ah0, ah1);
            *reinterpret_cast<uint2*>(Al + row * LDSU + f4 * 4) = make_uint2(al0, al1);
            *reinterpret_cast<uint2*>(Bh + row * LDSU + f4 * 4) = make_uint2(bh0, bh1);
            *reinterpret_cast<uint2*>(Bl + row * LDSU + f4 * 4) = make_uint2(bl0, bl1);
        }
        __syncthreads();
        bf16x8 ahi[2], alo[2];
#pragma unroll
        for (int rt = 0; rt < 2; ++rt) {
            int arow = wv * 32 + rt * 16 + c0l;
            ahi[rt] = *reinterpret_cast<const bf16x8*>(Ah + arow * LDSU + g * 8);
            alo[rt] = *reinterpret_cast<const bf16x8*>(Al + arow * LDSU + g * 8);
        }
#pragma unroll
        for (int ct = 0; ct < 8; ++ct) {
            int brow = ct * 16 + c0l;
            bf16x8 bhi = *reinterpret_cast<const bf16x8*>(Bh + brow * LDSU + g * 8);
            bf16x8 blo = *reinterpret_cast<const bf16x8*>(Bl + brow * LDSU + g * 8);
#pragma unroll
            for (int rt = 0; rt < 2; ++rt) {
                acc[rt][ct] = __builtin_amdgcn_mfma_f32_16x16x32_bf16(ahi[rt], bhi, acc[rt][ct], 0, 0, 0);
                acc[rt][ct] = __builtin_amdgcn_mfma_f32_16x16x32_bf16(ahi[rt], blo, acc[rt][ct], 0, 0, 0);
                acc[rt][ct] = __builtin_amdgcn_mfma_f32_16x16x32_bf16(alo[rt], bhi, acc[rt][ct], 0, 0, 0);
            }
        }
    }

    float ivb[8], ppc[8];
#pragma unroll
    for (int ct = 0; ct < 8; ++ct) {
        ivb[ct] = inv_s[cb + ct * 16 + c0l];
        ppc[ct] = pp[cb + ct * 16 + c0l];
    }
    float t3r[2][4][3];
#pragma unroll
    for (int rt = 0; rt < 2; ++rt)
#pragma unroll
        for (int v = 0; v < 4; ++v)
            t3r[rt][v][0] = t3r[rt][v][1] = t3r[rt][v][2] = INFINITY;
#pragma unroll
    for (int rt = 0; rt < 2; ++rt) {
        float iva[4], qqr[4];
#pragma unroll
        for (int v = 0; v < 4; ++v) {
            int row = rb + wv * 32 + rt * 16 + g * 4 + v;
            iva[v] = inv_q[row];
            qqr[v] = qq[row];
        }
#pragma unroll
        for (int ct = 0; ct < 8; ++ct) {
#pragma unroll
            for (int v = 0; v < 4; ++v) {
                float dot = acc[rt][ct][v] * iva[v] * ivb[ct];
                float d2 = qqr[v] + ppc[ct] - 2.0f * dot;
                float d = sqrtf(fmaxf(d2, 1e-12f));
                t3ins(t3r[rt][v], d);
            }
        }
    }
#pragma unroll
    for (int off = 1; off < 16; off <<= 1) {
#pragma unroll
        for (int rt = 0; rt < 2; ++rt)
#pragma unroll
            for (int v = 0; v < 4; ++v) {
                float o0 = __shfl_xor(t3r[rt][v][0], off, 64);
                float o1 = __shfl_xor(t3r[rt][v][1], off, 64);
                float o2 = __shfl_xor(t3r[rt][v][2], off, 64);
                t3ins(t3r[rt][v], o0);
                t3ins(t3r[rt][v], o1);
                t3ins(t3r[rt][v], o2);
            }
    }
    if (c0l == 0) {
#pragma unroll
        for (int rt = 0; rt < 2; ++rt)
#pragma unroll
            for (int v = 0; v < 4; ++v) {
                int row = rb + wv * 32 + rt * 16 + g * 4 + v;
                float* dst = top3part + ((size_t)cs * Q_ROWS + row) * 4;
                dst[0] = t3r[rt][v][0]; dst[1] = t3r[rt][v][1];
                dst[2] = t3r[rt][v][2]; dst[3] = 0.0f;
            }
    }
}

// ---------------------------------------------------------------------------
// Phase C (R20 proven, ~105us): FROZEN. Packed-word flag barrier + register-
// resident pre-scaled rows.
__launch_bounds__(1024)
__global__ void iterate_select(const float* __restrict__ qf, const float* __restrict__ inv_q,
                               const float* __restrict__ qq, const float* __restrict__ top3part,
                               float* __restrict__ out, float* __restrict__ candU,
                               int* __restrict__ candI, unsigned long long* __restrict__ packed) {
    __shared__ float t3s[CR][3];
    __shared__ float qqs[CR], scs[CR];
    __shared__ int kn[CR];
    __shared__ __align__(16) float qfc[DIM];
    __shared__ float red[CT / 64];
    __shared__ float bmin_sh;
    __shared__ unsigned long long pk_sh[CB];
    __shared__ int lidx[16];
    __shared__ int lidx_loc[SLOTS];
    __shared__ int lcnt, ccnt;

    int tid = threadIdx.x;
    int bid = blockIdx.x;
    int rbase = bid * CR;
    int lane = tid & 63, wv = tid >> 6;
    int row = tid >> 2, sub = tid & 3;   // 4 threads per row

    float4 rr[16];
    {
        float si = inv_q[rbase + row];
        const float4* rp = reinterpret_cast<const float4*>(qf + (size_t)(rbase + row) * DIM);
#pragma unroll
        for (int i = 0; i < 16; ++i) {
            float4 v = rp[sub + 4 * i];
            rr[i] = make_float4(v.x * si, v.y * si, v.z * si, v.w * si);
        }
    }
    if (tid < CR) {
        int r = rbase + tid;
        float b3[3] = {INFINITY, INFINITY, INFINITY};
        for (int csq = 0; csq < COLSPLIT; ++csq) {
            const float* p = top3part + ((size_t)csq * Q_ROWS + r) * 4;
            t3ins(b3, p[0]); t3ins(b3, p[1]); t3ins(b3, p[2]);
        }
        t3s[tid][0] = b3[0]; t3s[tid][1] = b3[1]; t3s[tid][2] = b3[2];
        qqs[tid] = qq[r];
        kn[tid] = 0;
    }
    __syncthreads();

    for (int t = 0; t <= N_SEL; ++t) {
        if (t > 0) {
            if (tid == 0) lcnt = 0;
            __syncthreads();
            if (wv == 0) {
                unsigned long long pv = (lane < CB) ? pk_sh[lane] : ~0ull;
                unsigned bb = (lane < CB) ? (unsigned)(pv >> 32) : 0xFFFFFFFFu;
                unsigned mb = bb;
#pragma unroll
                for (int o = 1; o < 64; o <<= 1) mb = min(mb, (unsigned)__shfl_xor((int)mb, o, 64));
                if (lane < CB && bb == mb) {
                    if (!(pv & 1ull)) {
                        int p = atomicAdd(&lcnt, 1);
                        if (p < 16) lidx[p] = (int)((pv >> 1) & 0x7FFFull);
                    } else {
                        for (int s2 = 0; s2 < SLOTS; ++s2) {
                            float u = candU[(t - 1) * CB * SLOTS + lane * SLOTS + s2];
                            if (__float_as_uint(u) == mb) {
                                int p = atomicAdd(&lcnt, 1);
                                if (p < 16) lidx[p] = candI[(t - 1) * CB * SLOTS + lane * SLOTS + s2];
                            }
                        }
                    }
                }
            }
            __syncthreads();
            int m = lcnt < 16 ? lcnt : 16;
            for (int j = 0; j < m; ++j) {
                int c = lidx[j];
                if (tid == 0 && c >= rbase && c < rbase + CR) kn[c - rbase] = 1;
                if (tid < 64) {
                    float4 v = reinterpret_cast<const float4*>(qf + (size_t)c * DIM)[tid];
                    float s = inv_q[c];
                    reinterpret_cast<float4*>(qfc)[tid] = make_float4(v.x * s, v.y * s, v.z * s, v.w * s);
                }
                __syncthreads();
                float qqc = qq[c];
                const float4* cp = reinterpret_cast<const float4*>(qfc);
                float d = 0.0f;
#pragma unroll
                for (int i2 = 0; i2 < 16; ++i2) {
                    float4 w = cp[sub + 4 * i2];
                    d += rr[i2].x * w.x;
                    d += rr[i2].y * w.y;
                    d += rr[i2].z * w.z;
                    d += rr[i2].w * w.w;
                }
                d += __shfl_xor(d, 1, 64);
                d += __shfl_xor(d, 2, 64);
                if (sub == 0) {
                    float d2 = qqs[row] + qqc - 2.0f * d;
                    float dist = sqrtf(fmaxf(d2, 1e-12f));
                    float b3[3] = {t3s[row][0], t3s[row][1], t3s[row][2]};
                    t3ins(b3, dist);
                    t3s[row][0] = b3[0]; t3s[row][1] = b3[1]; t3s[row][2] = b3[2];
                }
                __syncthreads();
            }
            __syncthreads();
        }

        if (t == N_SEL) {
            if (tid < CR)
                out[rbase + tid] = 1.0f - smean3(t3s[tid][0], t3s[tid][1], t3s[tid][2]);
            return;
        }

        if (tid == 0) ccnt = 0;
        if (tid < CR)
            scs[tid] = kn[tid] ? INFINITY : smean3(t3s[tid][0], t3s[tid][1], t3s[tid][2]);
        __syncthreads();

        float mn = (tid < CR) ? scs[tid] : INFINITY;
#pragma unroll
        for (int o = 1; o < 64; o <<= 1) mn = fminf(mn, __shfl_xor(mn, o, 64));
        if (lane == 0) red[wv] = mn;
        __syncthreads();
        if (tid == 0) {
            float v = red[0];
#pragma unroll
            for (int i = 1; i < CT / 64; ++i) v = fminf(v, red[i]);
            bmin_sh = v;
        }
        __syncthreads();
        float bmin = bmin_sh;
        if (tid < CR && scs[tid] == bmin) {
            int p = atomicAdd(&ccnt, 1);
            if (p < SLOTS) {
                candU[t * CB * SLOTS + bid * SLOTS + p] = scs[tid];
                candI[t * CB * SLOTS + bid * SLOTS + p] = rbase + tid;
                lidx_loc[p] = rbase + tid;
            }
        }
        __syncthreads();
        if (tid == 0) {
            for (int p = ccnt; p < SLOTS; ++p) {
                candU[t * CB * SLOTS + bid * SLOTS + p] = INFINITY;
                candI[t * CB * SLOTS + bid * SLOTS + p] = 0;
            }
            unsigned long long pk = ((unsigned long long)__float_as_uint(bmin) << 32)
                                  | ((unsigned long long)(unsigned)lidx_loc[0] << 1)
                                  | (ccnt > 1 ? 1ull : 0ull);
            __hip_atomic_store(&packed[(t * CB + bid) * PKS], pk,
                               __ATOMIC_RELEASE, __HIP_MEMORY_SCOPE_AGENT);
        }
        if (wv == 0) {
            for (;;) {
                unsigned long long pv = (lane < CB)
                    ? __hip_atomic_load(&packed[(t * CB + lane) * PKS], __ATOMIC_RELAXED, __HIP_MEMORY_SCOPE_AGENT)
                    : 0ull;
                bool ok = (lane >= CB) || (pv != ~0ull);
                if (__all(ok)) { if (lane < CB) pk_sh[lane] = pv; break; }
                __builtin_amdgcn_s_sleep(1);
            }
            __builtin_amdgcn_fence(__ATOMIC_ACQUIRE, "agent");
        }
        __syncthreads();
    }
}

// ---------------------------------------------------------------------------
extern "C" void kernel_launch(void* const* d_in, const int* in_sizes, int n_in,
                              void* d_out, int out_size, void* d_ws, size_t ws_size,
                              hipStream_t stream) {
    const float* sfeat = (const float*)d_in[0];
    const float* qfeat = (const float*)d_in[2];
    float* out = (float*)d_out;

    float* ws = (float*)d_ws;
    float* inv_q = ws + WS_INV_Q;
    float* qq    = ws + WS_QQ;
    float* inv_s = ws + WS_INV_S;
    float* pp    = ws + WS_PP;
    float* top3p = ws + WS_TOP3P;
    float* candU = ws + WS_CANDU;
    int* candI   = (int*)(ws + WS_CANDI);
    unsigned long long* packed = (unsigned long long*)(ws + WS_PACKED);

    int n_extra = out_size - Q_ROWS;
    if (n_extra < 0) n_extra = 0;

    norm_rows_all<<<(Q_ROWS + S_ROWS) * 64 / 256, 256, 0, stream>>>(
        qfeat, sfeat, inv_q, qq, inv_s, pp, packed, out, n_extra);
    knn_support_kernel<<<64 * COLSPLIT, 256, 0, stream>>>(qfeat, sfeat, inv_q, inv_s, qq, pp, top3p);

    const float* a0 = qfeat; const float* a1 = inv_q; const float* a2 = qq;
    const float* a3 = top3p; float* a4 = out;
    float* a5 = candU; int* a6 = candI; unsigned long long* a7 = packed;
    void* cargs[] = {&a0, &a1, &a2, &a3, &a4, &a5, &a6, &a7};
    hipLaunchCooperativeKernel(iterate_select, dim3(CB), dim3(CT), cargs, 0, stream);
}